// Round 2
// 166.696 us; speedup vs baseline: 1.0113x; 1.0113x over previous
//
#include <hip/hip_runtime.h>

// B=4, C=12, D=32, H=128, W=128. S = D*H*W = 524288 voxels per b.
// One pass: softmax over C, accumulate 32 scalars per b, finalize 4 losses.
// R1 post-mortem: 59us main kernel latency-bound (2 waves/SIMD, 18% occ).
// R2: grid 1024 blocks, accumulators 53->32 via algebra.
// R3 theory: launch_bounds(256,4) + float4 staging (48 VGPR live) forced
//   scratch spills; also 30 TRANS ops/voxel. Fix: float2 staging (24 VGPR,
//   peak live ~90 -> no spills at 4 waves/SIMD), slog via product
//   q=prod(1+p_c) (11 fma + 1 log instead of 12 logs), LSE without max
//   subtraction (args are probs in [0,1], exp range [1,e] -- safe).
// R4: identical resubmit (R3 bench was an infra failure, no data).

#define S2 262144           // S/2 float2 groups per (b,c) plane
#define BLOCKS_PER_B 256
#define THREADS 256
#define ITERS 4             // 4 float2 groups (8 voxels) per thread
#define NVOX 524288.0f
#define SMOOTH 1e-5f

#define WRED(v) { v += __shfl_down(v,32); v += __shfl_down(v,16); \
                  v += __shfl_down(v,8);  v += __shfl_down(v,4);  \
                  v += __shfl_down(v,2);  v += __shfl_down(v,1); }

// Per-voxel processing; COMP in {x,y}.
// id1 = t<=4 ? 2t+1 : t+5  (odd set + {10,11});  id2 = t<=3 ? 2t+2 : -1 (even set)
#define PROC2(COMP) do {                                                       \
  float xv[12];                                                                \
  _Pragma("unroll")                                                            \
  for (int c = 0; c < 12; ++c) xv[c] = x[c].COMP;                              \
  const int tgt = tg.COMP;                                                     \
  float m = xv[0];                                                             \
  _Pragma("unroll")                                                            \
  for (int c = 1; c < 12; ++c) m = fmaxf(m, xv[c]);                            \
  float e[12]; float es = 0.f;                                                 \
  _Pragma("unroll")                                                            \
  for (int c = 0; c < 12; ++c) { e[c] = __expf(xv[c] - m); es += e[c]; }       \
  const float r = __builtin_amdgcn_rcpf(es);                                   \
  float p[12];                                                                 \
  _Pragma("unroll")                                                            \
  for (int c = 0; c < 12; ++c) {                                               \
    p[c] = e[c] * r;                                                           \
    aZ[c] += p[c] * p[c];                                                      \
    aP[c] += p[c];                                                             \
  }                                                                            \
  /* sum_{c>=1} log(1+p_c) = log(prod(1+p_c)); q in [1, 2^11], exact range */  \
  float q = 1.f;                                                               \
  _Pragma("unroll")                                                            \
  for (int c = 1; c < 12; ++c) q = __builtin_fmaf(p[c], q, q);                 \
  const float g0 = p[0];                                                       \
  float g1 = 0.f, g2 = 0.f;                                                    \
  _Pragma("unroll")                                                            \
  for (int c = 1; c < 12; ++c) {                                               \
    if (c==1||c==3||c==5||c==7||c==9||c==10||c==11) g1 = (id1==c) ? p[c] : g1; \
    else                                            g2 = (id2==c) ? p[c] : g2; \
  }                                                                            \
  const bool t0 = (tgt == 0);                                                  \
  const bool t1 = (tgt == id1);                                                \
  const bool t2 = (tgt == id2);    /* id2==-1 never matches tgt>=0 */          \
  c0 += t0 ? 1.f : 0.f;  c1 += t1 ? 1.f : 0.f;  c2 += t2 ? 1.f : 0.f;          \
  p0S += t0 ? g0 : 0.f;  p1S += t1 ? g1 : 0.f;  p2S += t2 ? g2 : 0.f;          \
  const float pt = t1 ? g1 : (t2 ? g2 : 0.f);                                  \
  cesE += __logf(q * __builtin_amdgcn_rcpf(1.f + pt));                         \
  /* LSE over {g0,g1,(g2)}: all in [0,1] -> exp in [1,e], no max needed */     \
  float s3 = __expf(g0) + __expf(g1);                                          \
  if (v2) s3 += __expf(g2);                                                    \
  const float gt = t0 ? g0 : (t1 ? g1 : g2);                                   \
  ces += __logf(s3) - gt;                                                      \
} while (0)

__global__ void zero_acc(float* __restrict__ acc) {
  acc[threadIdx.x] = 0.f;   // 4 b * 64 slots
}

// Slot layout per b (stride 64):
//  0: ces (marg-CE NLL sum)   1: cesE (exc-CE sum)
//  2,3,4: cnt0,cnt1,cnt2      5,6,7: pTgt0,pTgt1,pTgt2
//  8..19: z[c] = sum p_c^2    20..31: pSum[c] = sum p_c
__global__ __launch_bounds__(THREADS, 4)
void marg_main(const float2* __restrict__ inp, const int2* __restrict__ tgtp,
               const int* __restrict__ task_id, float* __restrict__ acc) {
  const int b   = blockIdx.x / BLOCKS_PER_B;
  const int blk = blockIdx.x % BLOCKS_PER_B;
  const int t   = task_id[b];
  const int id1 = (t <= 4) ? 2*t + 1 : t + 5;
  const int id2 = (t <= 3) ? 2*t + 2 : -1;
  const bool v2 = (id2 >= 0);

  const float2* inB = inp  + (size_t)b * 12 * S2;
  const int2*   tgB = tgtp + (size_t)b * S2;

  float aZ[12], aP[12];
  #pragma unroll
  for (int c = 0; c < 12; ++c) { aZ[c]=0.f; aP[c]=0.f; }
  float ces=0.f, cesE=0.f, c0=0.f, c1=0.f, c2=0.f, p0S=0.f, p1S=0.f, p2S=0.f;

  #pragma unroll 1
  for (int it = 0; it < ITERS; ++it) {
    const int s = (blk * ITERS + it) * THREADS + (int)threadIdx.x;
    float2 x[12];
    #pragma unroll
    for (int c = 0; c < 12; ++c) x[c] = inB[c * S2 + s];
    const int2 tg = tgB[s];
    PROC2(x); PROC2(y);
  }

  WRED(ces); WRED(cesE); WRED(c0); WRED(c1); WRED(c2);
  WRED(p0S); WRED(p1S); WRED(p2S);
  #pragma unroll
  for (int c = 0; c < 12; ++c) { WRED(aZ[c]); WRED(aP[c]); }

  __shared__ float red[4][32];
  const int lane = threadIdx.x & 63;
  const int wv   = threadIdx.x >> 6;
  if (lane == 0) {
    float* rw = red[wv];
    rw[0]=ces; rw[1]=cesE; rw[2]=c0; rw[3]=c1; rw[4]=c2;
    rw[5]=p0S; rw[6]=p1S; rw[7]=p2S;
    #pragma unroll
    for (int c = 0; c < 12; ++c) { rw[8+c]=aZ[c]; rw[20+c]=aP[c]; }
  }
  __syncthreads();
  if (threadIdx.x < 32) {
    const float sv = red[0][threadIdx.x] + red[1][threadIdx.x]
                   + red[2][threadIdx.x] + red[3][threadIdx.x];
    atomicAdd(acc + b * 64 + threadIdx.x, sv);
  }
}

__global__ void finalize(const float* __restrict__ acc,
                         const int* __restrict__ task_id,
                         float* __restrict__ out) {
  if (threadIdx.x != 0) return;
  float lmd = 0.f, lmce = 0.f, led = 0.f, lece = 0.f;
  for (int b = 0; b < 4; ++b) {
    const float* a = acc + b * 64;
    const int t   = task_id[b];
    const int id1 = (t <= 4) ? 2*t + 1 : t + 5;
    const int id2 = (t <= 3) ? 2*t + 2 : -1;

    lmce += a[0] / NVOX;
    lece += a[1] / NVOX;

    // marginal dice: inter_j = pTgt_j, y_j = cnt_j, z_j = z[ids[j]]
    const float d0 = (2.f*a[5] + SMOOTH) / (a[8 + 0]   + a[2] + SMOOTH);
    const float d1 = (2.f*a[6] + SMOOTH) / (a[8 + id1] + a[3] + SMOOTH);
    float d2 = 1.f;
    if (id2 >= 0)
      d2 = (2.f*a[7] + SMOOTH) / (a[8 + id2] + a[4] + SMOOTH);
    lmd += (1.f - d0) + (1.f - d1) + (1.f - d2);

    // exclusion dice: c=0 -> te=0 -> SMOOTH/(z0+SMOOTH)
    led += SMOOTH / (a[8] + SMOOTH);
    for (int c = 1; c < 12; ++c) {
      const float ptc  = (c == id1) ? a[6] : ((c == id2) ? a[7] : 0.f);
      const float cntc = (c == id1) ? a[3] : ((c == id2) ? a[4] : 0.f);
      const float inter = a[20 + c] - ptc;
      const float ye    = NVOX - cntc;
      led += (2.f*inter + SMOOTH) / (a[8 + c] + ye + SMOOTH);
    }
  }
  out[0] = lmd  * 0.25f;
  out[1] = lmce * 0.25f;
  out[2] = led  * 0.25f;
  out[3] = lece * 0.25f;
}

extern "C" void kernel_launch(void* const* d_in, const int* in_sizes, int n_in,
                              void* d_out, int out_size, void* d_ws, size_t ws_size,
                              hipStream_t stream) {
  const float* inputs  = (const float*)d_in[0];
  const int*   targets = (const int*)d_in[1];
  const int*   task_id = (const int*)d_in[2];
  float* out = (float*)d_out;
  float* acc = (float*)d_ws;

  zero_acc<<<1, 256, 0, stream>>>(acc);
  marg_main<<<dim3(4 * BLOCKS_PER_B), THREADS, 0, stream>>>(
      (const float2*)inputs, (const int2*)targets, task_id, acc);
  finalize<<<1, 64, 0, stream>>>(acc, task_id, out);
}